// Round 1
// baseline (928.921 us; speedup 1.0000x reference)
//
#include <hip/hip_runtime.h>
#include <math.h>

#define Eo 768
#define Ho 12
#define Do 64
#define Ro 4
#define Bo 4
#define To 1024
#define SCALING 0.125f

// out[m][n] = sum_k X[m][k] * W[n][k] + bvec[n]   (x @ W^T + b)
// BM=BN=128, BK=16, 256 threads, 8x8 per thread.
__global__ __launch_bounds__(256) void gemm_xwt(
    const float* __restrict__ X, const float* __restrict__ W,
    const float* __restrict__ bvec, float* __restrict__ out,
    int M, int N, int K)
{
    __shared__ float Xs[16][128];
    __shared__ float Ws[16][128];
    const int tid = threadIdx.x;
    const int m0 = blockIdx.y * 128;
    const int n0 = blockIdx.x * 128;
    const int ty = tid >> 4, tx = tid & 15;
    const int lr = tid >> 1;            // 0..127 staging row
    const int lk = (tid & 1) * 8;       // k offset 0 or 8

    float acc[8][8];
#pragma unroll
    for (int i = 0; i < 8; ++i)
#pragma unroll
        for (int j = 0; j < 8; ++j) acc[i][j] = 0.f;

    const float* xp = &X[(size_t)(m0 + lr) * K + lk];
    const float* wp = &W[(size_t)(n0 + lr) * K + lk];

    for (int k0 = 0; k0 < K; k0 += 16) {
        float4 xa0 = *(const float4*)(xp + k0);
        float4 xa1 = *(const float4*)(xp + k0 + 4);
        float4 wb0 = *(const float4*)(wp + k0);
        float4 wb1 = *(const float4*)(wp + k0 + 4);
        __syncthreads();   // previous iteration's reads done
        Xs[lk+0][lr]=xa0.x; Xs[lk+1][lr]=xa0.y; Xs[lk+2][lr]=xa0.z; Xs[lk+3][lr]=xa0.w;
        Xs[lk+4][lr]=xa1.x; Xs[lk+5][lr]=xa1.y; Xs[lk+6][lr]=xa1.z; Xs[lk+7][lr]=xa1.w;
        Ws[lk+0][lr]=wb0.x; Ws[lk+1][lr]=wb0.y; Ws[lk+2][lr]=wb0.z; Ws[lk+3][lr]=wb0.w;
        Ws[lk+4][lr]=wb1.x; Ws[lk+5][lr]=wb1.y; Ws[lk+6][lr]=wb1.z; Ws[lk+7][lr]=wb1.w;
        __syncthreads();
#pragma unroll
        for (int kk = 0; kk < 16; ++kk) {
            float4 a0 = *(const float4*)&Xs[kk][ty*4];
            float4 a1 = *(const float4*)&Xs[kk][64 + ty*4];
            float4 b0 = *(const float4*)&Ws[kk][tx*4];
            float4 b1 = *(const float4*)&Ws[kk][64 + tx*4];
            float av[8] = {a0.x,a0.y,a0.z,a0.w,a1.x,a1.y,a1.z,a1.w};
            float bv[8] = {b0.x,b0.y,b0.z,b0.w,b1.x,b1.y,b1.z,b1.w};
#pragma unroll
            for (int i = 0; i < 8; ++i)
#pragma unroll
                for (int j = 0; j < 8; ++j)
                    acc[i][j] = fmaf(av[i], bv[j], acc[i][j]);
        }
    }

#pragma unroll
    for (int ih = 0; ih < 2; ++ih)
#pragma unroll
        for (int i = 0; i < 4; ++i) {
            int m = m0 + ih*64 + ty*4 + i;
#pragma unroll
            for (int jh = 0; jh < 2; ++jh) {
                int n = n0 + jh*64 + tx*4;
                float4 bb = *(const float4*)&bvec[n];
                float4 r;
                r.x = acc[ih*4+i][jh*4+0] + bb.x;
                r.y = acc[ih*4+i][jh*4+1] + bb.y;
                r.z = acc[ih*4+i][jh*4+2] + bb.z;
                r.w = acc[ih*4+i][jh*4+3] + bb.w;
                *(float4*)&out[(size_t)m * N + n] = r;
            }
        }
}

// One block per (b, h, 16-row Q tile). Flash-style online softmax over
// s-chunks of 64. Thread (tt = tid>>4, sg = tid&15):
//   scores for s = s0 + sg + 16*j (j=0..3), holds O[tt][sg*4 .. sg*4+3].
__global__ __launch_bounds__(256) void attn_kernel(
    const float* __restrict__ qkv,   // [B*T, 3E]
    const float* __restrict__ kdyn,  // [B*H*T, R, T]
    const int*   __restrict__ kpm,   // [B, T]  (0 = keep, nonzero = mask)
    const float* __restrict__ bias,  // [B*H, T, T]
    const float* __restrict__ red_w, // [R, D]
    const float* __restrict__ red_b, // [R]
    float* __restrict__ o)           // [B*T, E]
{
    __shared__ float Qs[16][68];
    __shared__ float Ks[64][68];
    __shared__ float Vs[64][68];
    __shared__ float Ps[16][68];
    __shared__ float qred[16][4];
    __shared__ float mrow[16];
    __shared__ float lrow[16];

    const int tid  = threadIdx.x;
    const int tile = blockIdx.x & 63;
    const int bh   = blockIdx.x >> 6;
    const int b    = bh / Ho;
    const int h    = bh % Ho;
    const int t0   = tile * 16;

    const int tt = tid >> 4;
    const int sg = tid & 15;
    const int d4 = sg * 4;

    // stage Q tile (row tt, cols d4..d4+3)
    {
        const float* src = &qkv[(size_t)(b*To + t0 + tt) * (3*Eo) + h*Do + d4];
        *(float4*)&Qs[tt][d4] = *(const float4*)src;
    }
    if (tid < 16) { mrow[tid] = -1e30f; lrow[tid] = 0.f; }
    __syncthreads();

    if (tid < 64) {
        int qt = tid >> 2, r = tid & 3;
        float s = red_b[r];
        for (int d = 0; d < 64; ++d) s = fmaf(Qs[qt][d], red_w[r*64 + d], s);
        qred[qt][r] = s;
    }
    __syncthreads();

    float acc[4] = {0.f, 0.f, 0.f, 0.f};
    const size_t qkv_k_base = (size_t)(b*To) * (3*Eo) + Eo  + h*Do;
    const size_t qkv_v_base = (size_t)(b*To) * (3*Eo) + 2*Eo + h*Do;
    const size_t kd_base    = (size_t)(bh*To + t0 + tt) * Ro * To;
    const size_t bias_base  = ((size_t)bh * To + t0 + tt) * To;
    const int    kpm_base   = b * To;

    for (int c = 0; c < 16; ++c) {
        const int s0 = c * 64;
        // stage K,V chunk [64][64]
#pragma unroll
        for (int i = 0; i < 4; ++i) {
            int row = tt + i * 16;
            *(float4*)&Ks[row][d4] = *(const float4*)&qkv[qkv_k_base + (size_t)(s0+row)*(3*Eo) + d4];
            *(float4*)&Vs[row][d4] = *(const float4*)&qkv[qkv_v_base + (size_t)(s0+row)*(3*Eo) + d4];
        }
        __syncthreads();

        // scores: thread handles s_local = sg + 16*j
        float sc[4] = {0.f, 0.f, 0.f, 0.f};
#pragma unroll
        for (int dd = 0; dd < 64; dd += 4) {
            float4 q = *(const float4*)&Qs[tt][dd];
#pragma unroll
            for (int j = 0; j < 4; ++j) {
                float4 k = *(const float4*)&Ks[sg + 16*j][dd];
                sc[j] = fmaf(q.x, k.x, sc[j]);
                sc[j] = fmaf(q.y, k.y, sc[j]);
                sc[j] = fmaf(q.z, k.z, sc[j]);
                sc[j] = fmaf(q.w, k.w, sc[j]);
            }
        }
#pragma unroll
        for (int j = 0; j < 4; ++j) sc[j] *= SCALING;
        // low-rank dynamic bias
#pragma unroll
        for (int r = 0; r < 4; ++r) {
            float qr = qred[tt][r];
            const float* kdp = &kdyn[kd_base + (size_t)r*To + s0];
#pragma unroll
            for (int j = 0; j < 4; ++j)
                sc[j] = fmaf(qr, kdp[sg + 16*j], sc[j]);
        }
        // attn_bias + mask
        {
            const float* bp = &bias[bias_base + s0];
#pragma unroll
            for (int j = 0; j < 4; ++j) sc[j] += bp[sg + 16*j];
        }
        {
            const int* mp = &kpm[kpm_base + s0];
#pragma unroll
            for (int j = 0; j < 4; ++j)
                if (mp[sg + 16*j]) sc[j] = -INFINITY;
        }

        // online softmax (reduce across the 16 lanes sharing tt)
        float cmax = fmaxf(fmaxf(sc[0], sc[1]), fmaxf(sc[2], sc[3]));
#pragma unroll
        for (int off = 1; off < 16; off <<= 1)
            cmax = fmaxf(cmax, __shfl_xor(cmax, off, 16));
        float m_old = mrow[tt];
        float m_new = fmaxf(m_old, cmax);
        float p[4], psum = 0.f;
#pragma unroll
        for (int j = 0; j < 4; ++j) { p[j] = __expf(sc[j] - m_new); psum += p[j]; }
#pragma unroll
        for (int off = 1; off < 16; off <<= 1)
            psum += __shfl_xor(psum, off, 16);
        float scale = __expf(m_old - m_new);
#pragma unroll
        for (int k = 0; k < 4; ++k) acc[k] *= scale;
        if (sg == 0) { mrow[tt] = m_new; lrow[tt] = lrow[tt] * scale + psum; }
#pragma unroll
        for (int j = 0; j < 4; ++j) Ps[tt][sg + 16*j] = p[j];
        __syncthreads();

        // PV: acc[0..3] (= O[tt][d4..d4+3]) += P[tt][s] * V[s][d4..d4+3]
#pragma unroll
        for (int sb = 0; sb < 64; sb += 4) {
            float4 p4 = *(const float4*)&Ps[tt][sb];
            float4 v;
            v = *(const float4*)&Vs[sb+0][d4];
            acc[0]=fmaf(p4.x,v.x,acc[0]); acc[1]=fmaf(p4.x,v.y,acc[1]);
            acc[2]=fmaf(p4.x,v.z,acc[2]); acc[3]=fmaf(p4.x,v.w,acc[3]);
            v = *(const float4*)&Vs[sb+1][d4];
            acc[0]=fmaf(p4.y,v.x,acc[0]); acc[1]=fmaf(p4.y,v.y,acc[1]);
            acc[2]=fmaf(p4.y,v.z,acc[2]); acc[3]=fmaf(p4.y,v.w,acc[3]);
            v = *(const float4*)&Vs[sb+2][d4];
            acc[0]=fmaf(p4.z,v.x,acc[0]); acc[1]=fmaf(p4.z,v.y,acc[1]);
            acc[2]=fmaf(p4.z,v.z,acc[2]); acc[3]=fmaf(p4.z,v.w,acc[3]);
            v = *(const float4*)&Vs[sb+3][d4];
            acc[0]=fmaf(p4.w,v.x,acc[0]); acc[1]=fmaf(p4.w,v.y,acc[1]);
            acc[2]=fmaf(p4.w,v.z,acc[2]); acc[3]=fmaf(p4.w,v.w,acc[3]);
        }
        __syncthreads();
    }

    float linv = 1.0f / lrow[tt];
    float4 ov = make_float4(acc[0]*linv, acc[1]*linv, acc[2]*linv, acc[3]*linv);
    *(float4*)&o[(size_t)(b*To + t0 + tt) * Eo + h*Do + d4] = ov;
}

extern "C" void kernel_launch(void* const* d_in, const int* in_sizes, int n_in,
                              void* d_out, int out_size, void* d_ws, size_t ws_size,
                              hipStream_t stream) {
    const float* query = (const float*)d_in[0];
    const float* kdyn  = (const float*)d_in[1];
    const int*   kpm   = (const int*)d_in[2];
    const float* bias  = (const float*)d_in[3];
    const float* in_w  = (const float*)d_in[4];
    const float* in_b  = (const float*)d_in[5];
    const float* red_w = (const float*)d_in[6];
    const float* red_b = (const float*)d_in[7];
    const float* out_w = (const float*)d_in[8];
    const float* out_b = (const float*)d_in[9];
    float* out = (float*)d_out;

    float* qkv = (float*)d_ws;                        // [4096, 2304]
    float* o   = qkv + (size_t)4096 * 2304;           // [4096, 768]

    const int M = Bo * To;          // 4096
    dim3 g1((3*Eo)/128, M/128);     // (18, 32)
    gemm_xwt<<<g1, 256, 0, stream>>>(query, in_w, in_b, qkv, M, 3*Eo, Eo);

    attn_kernel<<<dim3(Bo*Ho*(To/16)), 256, 0, stream>>>(qkv, kdyn, kpm, bias, red_w, red_b, o);

    dim3 g3(Eo/128, M/128);         // (6, 32)
    gemm_xwt<<<g3, 256, 0, stream>>>(o, out_w, out_b, out, M, Eo, Eo);
}

// Round 2
// 418.180 us; speedup vs baseline: 2.2213x; 2.2213x over previous
//
#include <hip/hip_runtime.h>
#include <math.h>

typedef __attribute__((ext_vector_type(8))) short s16x8;
typedef __attribute__((ext_vector_type(4))) float f32x4;

#define MFMA(a,b,c) __builtin_amdgcn_mfma_f32_16x16x32_bf16((a),(b),(c),0,0,0)

__device__ __forceinline__ unsigned short f2bf(float f){
    unsigned u = __builtin_bit_cast(unsigned, f);
    u += 0x7FFFu + ((u >> 16) & 1u);
    return (unsigned short)(u >> 16);
}

// ---------------------------------------------------------------------------
// C[m][n] = sum_k X[m][k]*W[n][k] + bvec[n]  (x @ W^T + b), f32 in/out,
// bf16 MFMA inside. BM=BN=128, BK=64, 256 threads (4 waves, 64x64 quadrants).
// LDS tiles are [row][64] bf16 with 16B-granule XOR swizzle: granule g of row
// r is stored at slot g ^ (r&7)  -> conflict-free ds_read_b128 fragments.
// ---------------------------------------------------------------------------
__global__ __launch_bounds__(256) void gemm_mfma(
    const float* __restrict__ X, const float* __restrict__ W,
    const float* __restrict__ bvec, float* __restrict__ out,
    int N, int K)
{
    __shared__ __align__(16) unsigned short Al[128*64];
    __shared__ __align__(16) unsigned short Bl[128*64];
    const int tid = threadIdx.x;
    const int m0 = blockIdx.y*128, n0 = blockIdx.x*128;
    const int w = tid>>6, lane = tid&63, g = lane>>4, cc = lane&15;
    const int srow = tid>>1, kh = (tid&1)*32;       // staging: row, k-half
    const int arow_base = (w>>1)*64, brow_base = (w&1)*64;

    f32x4 acc[4][4];
#pragma unroll
    for (int i=0;i<4;i++)
#pragma unroll
        for (int j=0;j<4;j++) acc[i][j] = (f32x4){0.f,0.f,0.f,0.f};

    const float* xp = X + (size_t)(m0+srow)*K + kh;
    const float* wp = W + (size_t)(n0+srow)*K + kh;

    for (int kt = 0; kt < K; kt += 64) {
        float4 xv[8], wv[8];
#pragma unroll
        for (int i=0;i<8;i++){
            xv[i] = *(const float4*)(xp + kt + i*4);
            wv[i] = *(const float4*)(wp + kt + i*4);
        }
        __syncthreads();    // previous iteration's fragment reads done
#pragma unroll
        for (int q=0;q<4;q++){
            alignas(16) unsigned short ta[8], tb[8];
            float4 a0=xv[2*q], a1=xv[2*q+1], b0=wv[2*q], b1=wv[2*q+1];
            ta[0]=f2bf(a0.x); ta[1]=f2bf(a0.y); ta[2]=f2bf(a0.z); ta[3]=f2bf(a0.w);
            ta[4]=f2bf(a1.x); ta[5]=f2bf(a1.y); ta[6]=f2bf(a1.z); ta[7]=f2bf(a1.w);
            tb[0]=f2bf(b0.x); tb[1]=f2bf(b0.y); tb[2]=f2bf(b0.z); tb[3]=f2bf(b0.w);
            tb[4]=f2bf(b1.x); tb[5]=f2bf(b1.y); tb[6]=f2bf(b1.z); tb[7]=f2bf(b1.w);
            const int gr = (kh>>3) + q;
            const int sw = ((gr ^ (srow&7))<<3);
            *(s16x8*)&Al[srow*64 + sw] = *(const s16x8*)ta;
            *(s16x8*)&Bl[srow*64 + sw] = *(const s16x8*)tb;
        }
        __syncthreads();
#pragma unroll
        for (int ks=0;ks<2;ks++){
            s16x8 af[4], bfr[4];
#pragma unroll
            for (int i=0;i<4;i++){
                const int ra = arow_base + i*16 + cc;
                const int rb = brow_base + i*16 + cc;
                af[i]  = *(const s16x8*)&Al[ra*64 + (((ks*4+g) ^ (ra&7))<<3)];
                bfr[i] = *(const s16x8*)&Bl[rb*64 + (((ks*4+g) ^ (rb&7))<<3)];
            }
#pragma unroll
            for (int i=0;i<4;i++)
#pragma unroll
                for (int j=0;j<4;j++)
                    acc[i][j] = MFMA(af[i], bfr[j], acc[i][j]);
        }
    }
#pragma unroll
    for (int j=0;j<4;j++){
        const int n = n0 + brow_base + j*16 + cc;
        const float bb = bvec[n];
#pragma unroll
        for (int i=0;i<4;i++){
            const int mb = m0 + arow_base + i*16 + g*4;
#pragma unroll
            for (int r=0;r<4;r++)
                out[(size_t)(mb+r)*N + n] = acc[i][j][r] + bb;
        }
    }
}

// ---------------------------------------------------------------------------
// Flash attention with low-rank dynamic bias.
// Block = (q-tile of 64 rows, bh). 256 threads = 4 waves; wave wq owns q-rows
// [wq*16, wq*16+16). s-chunks of 64. Q pre-scaled (x0.125) bf16 fragments in
// registers. K bf16 [s][d] swizzled; V bf16 transposed [d][s] swizzled.
// dyn tile (qred.kdyn + bias + mask) computed with lane-owns-16-contiguous-s
// (all float4 global loads), exchanged via padded f32 LDS into MFMA C-layout.
// ---------------------------------------------------------------------------
__global__ __launch_bounds__(256) void attn_mfma(
    const float* __restrict__ qkv,   // [4096][2304]
    const float* __restrict__ kdyn,  // [B*H*T][4][1024]
    const int*   __restrict__ kpm,   // [B][1024]
    const float* __restrict__ bias,  // [B*H][1024][1024]
    const float* __restrict__ red_w, // [4][64]
    const float* __restrict__ red_b, // [4]
    float* __restrict__ o)           // [4096][768]
{
    __shared__ __align__(16) unsigned short Qlds[64*64];
    __shared__ __align__(16) unsigned short Klds[64*64];
    __shared__ __align__(16) unsigned short Vt[64*64];
    __shared__ __align__(16) float dynl[4][16*68];       // per wave [t][s+pad]
    __shared__ __align__(16) unsigned short Plds[4][16*64];
    __shared__ __align__(16) float qred_s[64][4];

    const int tid = threadIdx.x;
    const int qt = blockIdx.x;           // 0..15
    const int bh = blockIdx.y;           // 0..47
    const int b = bh / 12, h = bh % 12;
    const int t0 = qt*64;
    const int wq = tid>>6, lane = tid&63, g = lane>>4, cc = lane&15;

    // ---- prologue: stage Q (scaled, bf16, swizzled)
    {
        const int row = tid>>2, cb = (tid&3)*16;
        const float* src = qkv + (size_t)(b*1024 + t0 + row)*2304 + h*64 + cb;
        float4 v[4];
#pragma unroll
        for (int i=0;i<4;i++) v[i] = *(const float4*)(src + i*4);
#pragma unroll
        for (int q2=0;q2<2;q2++){
            alignas(16) unsigned short t8[8];
            float4 a0 = v[2*q2], a1 = v[2*q2+1];
            t8[0]=f2bf(a0.x*0.125f); t8[1]=f2bf(a0.y*0.125f);
            t8[2]=f2bf(a0.z*0.125f); t8[3]=f2bf(a0.w*0.125f);
            t8[4]=f2bf(a1.x*0.125f); t8[5]=f2bf(a1.y*0.125f);
            t8[6]=f2bf(a1.z*0.125f); t8[7]=f2bf(a1.w*0.125f);
            const int gr = (cb>>3) + q2;
            *(s16x8*)&Qlds[row*64 + ((gr ^ (row&7))<<3)] = *(const s16x8*)t8;
        }
    }
    // ---- prologue: q_red (from UNSCALED f32 q)
    {
        const int t = tid>>2, r = tid&3;
        const float* src = qkv + (size_t)(b*1024 + t0 + t)*2304 + h*64;
        float s = red_b[r];
#pragma unroll
        for (int d=0; d<64; d+=4){
            float4 q4 = *(const float4*)(src + d);
            float4 w4 = *(const float4*)(red_w + r*64 + d);
            s += q4.x*w4.x + q4.y*w4.y + q4.z*w4.z + q4.w*w4.w;
        }
        qred_s[t][r] = s;
    }
    __syncthreads();

    // Q fragments (fixed for all chunks)
    s16x8 qf[2];
#pragma unroll
    for (int ks=0;ks<2;ks++){
        const int row = wq*16 + cc;
        qf[ks] = *(const s16x8*)&Qlds[row*64 + (((ks*4+g) ^ (row&7))<<3)];
    }
    const float4 qr4 = *(const float4*)&qred_s[wq*16 + cc][0];

    f32x4 accO[4];
#pragma unroll
    for (int i=0;i<4;i++) accO[i] = (f32x4){0.f,0.f,0.f,0.f};
    float mrow_[4], lrow_[4];
#pragma unroll
    for (int r=0;r<4;r++){ mrow_[r] = -1e30f; lrow_[r] = 0.f; }

    const int srow = tid>>2, scb = (tid&3)*16;   // K/V staging: s-row, d-range
    const size_t kbase = (size_t)(b*1024)*2304 + 768  + h*64;
    const size_t vbase = (size_t)(b*1024)*2304 + 1536 + h*64;
    const int t_glob = t0 + wq*16 + cc;          // dyn phase: lane's q row
    const size_t kd_base = ((size_t)(bh*1024 + t_glob))*4096;
    const size_t bias_base = ((size_t)bh*1024 + t_glob)*1024;

    for (int c64 = 0; c64 < 16; ++c64) {
        const int s0 = c64*64;
        // ---- stage K (bf16, swizzled)
        {
            const float* kp = qkv + kbase + (size_t)(s0+srow)*2304 + scb;
            float4 v[4];
#pragma unroll
            for (int i=0;i<4;i++) v[i] = *(const float4*)(kp + i*4);
#pragma unroll
            for (int q2=0;q2<2;q2++){
                alignas(16) unsigned short t8[8];
                float4 a0 = v[2*q2], a1 = v[2*q2+1];
                t8[0]=f2bf(a0.x); t8[1]=f2bf(a0.y); t8[2]=f2bf(a0.z); t8[3]=f2bf(a0.w);
                t8[4]=f2bf(a1.x); t8[5]=f2bf(a1.y); t8[6]=f2bf(a1.z); t8[7]=f2bf(a1.w);
                const int gr = (scb>>3) + q2;
                *(s16x8*)&Klds[srow*64 + ((gr ^ (srow&7))<<3)] = *(const s16x8*)t8;
            }
        }
        // ---- stage V transposed (bf16 scatter, swizzled)
        {
            const float* vp = qkv + vbase + (size_t)(s0+srow)*2304 + scb;
            float vv[16];
#pragma unroll
            for (int i=0;i<4;i++){
                float4 t4 = *(const float4*)(vp + i*4);
                vv[4*i]=t4.x; vv[4*i+1]=t4.y; vv[4*i+2]=t4.z; vv[4*i+3]=t4.w;
            }
#pragma unroll
            for (int e=0;e<16;e++){
                const int d = scb + e;
                Vt[d*64 + (((srow>>3) ^ (d&7))<<3) + (srow&7)] = f2bf(vv[e]);
            }
        }
        // ---- dyn tile: lane owns (t = cc of wave strip, s = g*16..g*16+15)
        {
            float dyn[16];
            float4 bb[4]; int4 mm[4];
            const float* bp = bias + bias_base + s0 + g*16;
            const int*   mp = kpm + b*1024 + s0 + g*16;
#pragma unroll
            for (int i=0;i<4;i++){
                bb[i] = *(const float4*)(bp + i*4);
                mm[i] = *(const int4*)(mp + i*4);
            }
#pragma unroll
            for (int i=0;i<16;i++) dyn[i] = 0.f;
#pragma unroll
            for (int r=0;r<4;r++){
                const float* kp = kdyn + kd_base + (size_t)r*1024 + s0 + g*16;
                const float qr = (r==0)?qr4.x:(r==1)?qr4.y:(r==2)?qr4.z:qr4.w;
#pragma unroll
                for (int i=0;i<4;i++){
                    float4 kv = *(const float4*)(kp + i*4);
                    dyn[4*i+0] = fmaf(qr, kv.x, dyn[4*i+0]);
                    dyn[4*i+1] = fmaf(qr, kv.y, dyn[4*i+1]);
                    dyn[4*i+2] = fmaf(qr, kv.z, dyn[4*i+2]);
                    dyn[4*i+3] = fmaf(qr, kv.w, dyn[4*i+3]);
                }
            }
#pragma unroll
            for (int i=0;i<4;i++){
                dyn[4*i+0] = mm[i].x ? -__builtin_inff() : dyn[4*i+0] + bb[i].x;
                dyn[4*i+1] = mm[i].y ? -__builtin_inff() : dyn[4*i+1] + bb[i].y;
                dyn[4*i+2] = mm[i].z ? -__builtin_inff() : dyn[4*i+2] + bb[i].z;
                dyn[4*i+3] = mm[i].w ? -__builtin_inff() : dyn[4*i+3] + bb[i].w;
            }
            float* dst = &dynl[wq][cc*68 + g*16];
#pragma unroll
            for (int i=0;i<4;i++)
                *(float4*)(dst + i*4) = make_float4(dyn[4*i],dyn[4*i+1],dyn[4*i+2],dyn[4*i+3]);
        }
        __syncthreads();   // staging visible to all waves

        // ---- QK^T (scores pre-scaled via Q)
        f32x4 sc[4];
#pragma unroll
        for (int sq=0;sq<4;sq++){
            f32x4 z = (f32x4){0.f,0.f,0.f,0.f};
#pragma unroll
            for (int ks=0;ks<2;ks++){
                const int rowk = sq*16 + cc;
                s16x8 kf = *(const s16x8*)&Klds[rowk*64 + (((ks*4+g) ^ (rowk&7))<<3)];
                z = MFMA(qf[ks], kf, z);
            }
            sc[sq] = z;
        }
        // ---- + dyn, online softmax, P -> LDS (intra-wave)
        float sscale[4];
#pragma unroll
        for (int r=0;r<4;r++){
            const int trow = g*4 + r;
            float v[4];
#pragma unroll
            for (int sq=0;sq<4;sq++)
                v[sq] = sc[sq][r] + dynl[wq][trow*68 + sq*16 + cc];
            float mx = fmaxf(fmaxf(v[0],v[1]), fmaxf(v[2],v[3]));
#pragma unroll
            for (int off=1; off<16; off<<=1) mx = fmaxf(mx, __shfl_xor(mx, off));
            const float mn = fmaxf(mrow_[r], mx);
            float ps = 0.f;
#pragma unroll
            for (int sq=0;sq<4;sq++){ v[sq] = __expf(v[sq]-mn); ps += v[sq]; }
#pragma unroll
            for (int off=1; off<16; off<<=1) ps += __shfl_xor(ps, off);
            const float scl = __expf(mrow_[r]-mn);
            mrow_[r] = mn; lrow_[r] = lrow_[r]*scl + ps;
            sscale[r] = scl;
#pragma unroll
            for (int sq=0;sq<4;sq++){
                const int col = sq*16 + cc;
                Plds[wq][trow*64 + ((((col>>3)) ^ (trow&7))<<3) + (col&7)] = f2bf(v[sq]);
            }
        }
#pragma unroll
        for (int dq=0;dq<4;dq++){
            f32x4 a = accO[dq];
            a[0]*=sscale[0]; a[1]*=sscale[1]; a[2]*=sscale[2]; a[3]*=sscale[3];
            accO[dq] = a;
        }
        // ---- PV (P rows are intra-wave: same wave wrote them)
#pragma unroll
        for (int ks=0;ks<2;ks++){
            s16x8 pf = *(const s16x8*)&Plds[wq][cc*64 + (((ks*4+g) ^ (cc&7))<<3)];
#pragma unroll
            for (int dq=0;dq<4;dq++){
                const int rowv = dq*16 + cc;
                s16x8 vf = *(const s16x8*)&Vt[rowv*64 + (((ks*4+g) ^ (rowv&7))<<3)];
                accO[dq] = MFMA(pf, vf, accO[dq]);
            }
        }
        __syncthreads();   // protect K/V/dyn overwrite next chunk
    }

    // ---- epilogue: O = acc / l, f32
#pragma unroll
    for (int dq=0;dq<4;dq++){
#pragma unroll
        for (int r=0;r<4;r++){
            const int t = t0 + wq*16 + g*4 + r;
            o[(size_t)(b*1024 + t)*768 + h*64 + dq*16 + cc] = accO[dq][r] / lrow_[r];
        }
    }
}

extern "C" void kernel_launch(void* const* d_in, const int* in_sizes, int n_in,
                              void* d_out, int out_size, void* d_ws, size_t ws_size,
                              hipStream_t stream) {
    const float* query = (const float*)d_in[0];
    const float* kdyn  = (const float*)d_in[1];
    const int*   kpm   = (const int*)d_in[2];
    const float* bias  = (const float*)d_in[3];
    const float* in_w  = (const float*)d_in[4];
    const float* in_b  = (const float*)d_in[5];
    const float* red_w = (const float*)d_in[6];
    const float* red_b = (const float*)d_in[7];
    const float* out_w = (const float*)d_in[8];
    const float* out_b = (const float*)d_in[9];
    float* out = (float*)d_out;

    float* qkv = (float*)d_ws;                 // [4096][2304] f32
    float* o   = qkv + (size_t)4096*2304;      // [4096][768]  f32

    gemm_mfma<<<dim3(18,32), 256, 0, stream>>>(query, in_w, in_b, qkv, 2304, 768);
    attn_mfma<<<dim3(16,48), 256, 0, stream>>>(qkv, kdyn, kpm, bias, red_w, red_b, o);
    gemm_mfma<<<dim3(6,32),  256, 0, stream>>>(o, out_w, out_b, out, 768, 768);
}

// Round 3
// 362.548 us; speedup vs baseline: 2.5622x; 1.1534x over previous
//
#include <hip/hip_runtime.h>
#include <math.h>

typedef __attribute__((ext_vector_type(8))) short s16x8;
typedef __attribute__((ext_vector_type(4))) float f32x4;

#define MFMA(a,b,c) __builtin_amdgcn_mfma_f32_16x16x32_bf16((a),(b),(c),0,0,0)

__device__ __forceinline__ unsigned short f2bf(float f){
    unsigned u = __builtin_bit_cast(unsigned, f);
    u += 0x7FFFu + ((u >> 16) & 1u);
    return (unsigned short)(u >> 16);
}
__device__ __forceinline__ float bf2f(unsigned short u){
    return __builtin_bit_cast(float, ((unsigned)u) << 16);
}
__device__ __forceinline__ float4 fma4(float s, float4 a, float4 c){
    c.x = fmaf(s, a.x, c.x); c.y = fmaf(s, a.y, c.y);
    c.z = fmaf(s, a.z, c.z); c.w = fmaf(s, a.w, c.w);
    return c;
}

// ---------------------------------------------------------------------------
// QKV projection: qkv = query @ in_w^T + in_b, emitted as:
//   qs [48][1024][64] bf16  (q * 0.125)
//   kb [48][1024][64] bf16
//   vt [48][64][1024] bf16  (transposed)
// BM=BN=128, BK=64, 256 threads, bf16 MFMA, XOR-swizzled LDS.
// ---------------------------------------------------------------------------
__global__ __launch_bounds__(256) void gemm_qkv(
    const float* __restrict__ X, const float* __restrict__ W,
    const float* __restrict__ bvec,
    unsigned short* __restrict__ qs,
    unsigned short* __restrict__ kb,
    unsigned short* __restrict__ vtb)
{
    __shared__ __align__(16) unsigned short Al[128*64];
    __shared__ __align__(16) unsigned short Bl[128*64];
    const int tid = threadIdx.x;
    const int m0 = blockIdx.y*128, n0 = blockIdx.x*128;
    const int w = tid>>6, lane = tid&63, g = lane>>4, cc = lane&15;
    const int srow = tid>>1, kh = (tid&1)*32;
    const int arow_base = (w>>1)*64, brow_base = (w&1)*64;

    f32x4 acc[4][4];
#pragma unroll
    for (int i=0;i<4;i++)
#pragma unroll
        for (int j=0;j<4;j++) acc[i][j] = (f32x4){0.f,0.f,0.f,0.f};

    const float* xp = X + (size_t)(m0+srow)*768 + kh;
    const float* wp = W + (size_t)(n0+srow)*768 + kh;

    for (int kt = 0; kt < 768; kt += 64) {
        float4 xv[8], wv[8];
#pragma unroll
        for (int i=0;i<8;i++){
            xv[i] = *(const float4*)(xp + kt + i*4);
            wv[i] = *(const float4*)(wp + kt + i*4);
        }
        __syncthreads();
#pragma unroll
        for (int q=0;q<4;q++){
            alignas(16) unsigned short ta[8], tb[8];
            float4 a0=xv[2*q], a1=xv[2*q+1], b0=wv[2*q], b1=wv[2*q+1];
            ta[0]=f2bf(a0.x); ta[1]=f2bf(a0.y); ta[2]=f2bf(a0.z); ta[3]=f2bf(a0.w);
            ta[4]=f2bf(a1.x); ta[5]=f2bf(a1.y); ta[6]=f2bf(a1.z); ta[7]=f2bf(a1.w);
            tb[0]=f2bf(b0.x); tb[1]=f2bf(b0.y); tb[2]=f2bf(b0.z); tb[3]=f2bf(b0.w);
            tb[4]=f2bf(b1.x); tb[5]=f2bf(b1.y); tb[6]=f2bf(b1.z); tb[7]=f2bf(b1.w);
            const int gr = (kh>>3) + q;
            const int sw = ((gr ^ (srow&7))<<3);
            *(s16x8*)&Al[srow*64 + sw] = *(const s16x8*)ta;
            *(s16x8*)&Bl[srow*64 + sw] = *(const s16x8*)tb;
        }
        __syncthreads();
#pragma unroll
        for (int ks=0;ks<2;ks++){
            s16x8 af[4], bfr[4];
#pragma unroll
            for (int i=0;i<4;i++){
                const int ra = arow_base + i*16 + cc;
                const int rb = brow_base + i*16 + cc;
                af[i]  = *(const s16x8*)&Al[ra*64 + (((ks*4+g) ^ (ra&7))<<3)];
                bfr[i] = *(const s16x8*)&Bl[rb*64 + (((ks*4+g) ^ (rb&7))<<3)];
            }
#pragma unroll
            for (int i=0;i<4;i++)
#pragma unroll
                for (int j=0;j<4;j++)
                    acc[i][j] = MFMA(af[i], bfr[j], acc[i][j]);
        }
    }

    const int region = blockIdx.x / 6;   // 0:q 1:k 2:v  (block spans one region)
#pragma unroll
    for (int j=0;j<4;j++){
        const int n = n0 + brow_base + j*16 + cc;
        const float bb = bvec[n];
        const int nn = n - region*768;
        const int h = nn >> 6, d = nn & 63;
        if (region == 0){
#pragma unroll
            for (int i=0;i<4;i++){
                const int m = m0 + arow_base + i*16 + g*4;
                const int bq = m >> 10, t = m & 1023;
                unsigned short* dst = qs + ((size_t)(bq*12+h)*1024 + t)*64 + d;
#pragma unroll
                for (int r=0;r<4;r++)
                    dst[(size_t)r*64] = f2bf((acc[i][j][r] + bb)*0.125f);
            }
        } else if (region == 1){
#pragma unroll
            for (int i=0;i<4;i++){
                const int m = m0 + arow_base + i*16 + g*4;
                const int bq = m >> 10, t = m & 1023;
                unsigned short* dst = kb + ((size_t)(bq*12+h)*1024 + t)*64 + d;
#pragma unroll
                for (int r=0;r<4;r++)
                    dst[(size_t)r*64] = f2bf(acc[i][j][r] + bb);
            }
        } else {
#pragma unroll
            for (int i=0;i<4;i++){
                const int m = m0 + arow_base + i*16 + g*4;
                const int bq = m >> 10, t = m & 1023;
                ushort4 pk;
                pk.x = f2bf(acc[i][j][0] + bb);
                pk.y = f2bf(acc[i][j][1] + bb);
                pk.z = f2bf(acc[i][j][2] + bb);
                pk.w = f2bf(acc[i][j][3] + bb);
                *(ushort4*)&vtb[((size_t)(bq*12+h)*64 + d)*1024 + t] = pk;
            }
        }
    }
}

// ---------------------------------------------------------------------------
// Generic x @ W^T + b (f32 in/out) for the output projection.
// ---------------------------------------------------------------------------
__global__ __launch_bounds__(256) void gemm_mfma(
    const float* __restrict__ X, const float* __restrict__ W,
    const float* __restrict__ bvec, float* __restrict__ out,
    int N, int K)
{
    __shared__ __align__(16) unsigned short Al[128*64];
    __shared__ __align__(16) unsigned short Bl[128*64];
    const int tid = threadIdx.x;
    const int m0 = blockIdx.y*128, n0 = blockIdx.x*128;
    const int w = tid>>6, lane = tid&63, g = lane>>4, cc = lane&15;
    const int srow = tid>>1, kh = (tid&1)*32;
    const int arow_base = (w>>1)*64, brow_base = (w&1)*64;

    f32x4 acc[4][4];
#pragma unroll
    for (int i=0;i<4;i++)
#pragma unroll
        for (int j=0;j<4;j++) acc[i][j] = (f32x4){0.f,0.f,0.f,0.f};

    const float* xp = X + (size_t)(m0+srow)*K + kh;
    const float* wp = W + (size_t)(n0+srow)*K + kh;

    for (int kt = 0; kt < K; kt += 64) {
        float4 xv[8], wv[8];
#pragma unroll
        for (int i=0;i<8;i++){
            xv[i] = *(const float4*)(xp + kt + i*4);
            wv[i] = *(const float4*)(wp + kt + i*4);
        }
        __syncthreads();
#pragma unroll
        for (int q=0;q<4;q++){
            alignas(16) unsigned short ta[8], tb[8];
            float4 a0=xv[2*q], a1=xv[2*q+1], b0=wv[2*q], b1=wv[2*q+1];
            ta[0]=f2bf(a0.x); ta[1]=f2bf(a0.y); ta[2]=f2bf(a0.z); ta[3]=f2bf(a0.w);
            ta[4]=f2bf(a1.x); ta[5]=f2bf(a1.y); ta[6]=f2bf(a1.z); ta[7]=f2bf(a1.w);
            tb[0]=f2bf(b0.x); tb[1]=f2bf(b0.y); tb[2]=f2bf(b0.z); tb[3]=f2bf(b0.w);
            tb[4]=f2bf(b1.x); tb[5]=f2bf(b1.y); tb[6]=f2bf(b1.z); tb[7]=f2bf(b1.w);
            const int gr = (kh>>3) + q;
            const int sw = ((gr ^ (srow&7))<<3);
            *(s16x8*)&Al[srow*64 + sw] = *(const s16x8*)ta;
            *(s16x8*)&Bl[srow*64 + sw] = *(const s16x8*)tb;
        }
        __syncthreads();
#pragma unroll
        for (int ks=0;ks<2;ks++){
            s16x8 af[4], bfr[4];
#pragma unroll
            for (int i=0;i<4;i++){
                const int ra = arow_base + i*16 + cc;
                const int rb = brow_base + i*16 + cc;
                af[i]  = *(const s16x8*)&Al[ra*64 + (((ks*4+g) ^ (ra&7))<<3)];
                bfr[i] = *(const s16x8*)&Bl[rb*64 + (((ks*4+g) ^ (rb&7))<<3)];
            }
#pragma unroll
            for (int i=0;i<4;i++)
#pragma unroll
                for (int j=0;j<4;j++)
                    acc[i][j] = MFMA(af[i], bfr[j], acc[i][j]);
        }
    }
#pragma unroll
    for (int j=0;j<4;j++){
        const int n = n0 + brow_base + j*16 + cc;
        const float bb = bvec[n];
#pragma unroll
        for (int i=0;i<4;i++){
            const int mb = m0 + arow_base + i*16 + g*4;
#pragma unroll
            for (int r=0;r<4;r++)
                out[(size_t)(mb+r)*N + n] = acc[i][j][r] + bb;
        }
    }
}

// ---------------------------------------------------------------------------
// Flash attention, pipelined (T14): chunk c+1's K/V/kdyn/bias/mask loads are
// issued into registers while chunk c's QK/softmax/PV runs.
// Block = (64 q-rows, bh), 4 waves; wave owns 16 q-rows. s-chunks of 64.
// ---------------------------------------------------------------------------
__global__ __launch_bounds__(256) void attn_mfma(
    const unsigned short* __restrict__ qs,   // [48][1024][64] bf16 (scaled)
    const unsigned short* __restrict__ kbf,  // [48][1024][64] bf16
    const unsigned short* __restrict__ vtf,  // [48][64][1024] bf16
    const float* __restrict__ kdyn,          // [48*1024][4][1024]
    const int*   __restrict__ kpm,           // [4][1024]
    const float* __restrict__ bias,          // [48][1024][1024]
    const float* __restrict__ red_w,         // [4][64]
    const float* __restrict__ red_b,         // [4]
    float* __restrict__ o)                   // [4096][768]
{
    __shared__ __align__(16) unsigned short Qlds[64*64];
    __shared__ __align__(16) unsigned short Klds[64*64];
    __shared__ __align__(16) unsigned short Vtl[64*64];
    __shared__ __align__(16) float dynl[4][16*66];
    __shared__ __align__(16) unsigned short Plds[4][16*64];
    __shared__ float qred_s[64][4];

    const int tid = threadIdx.x;
    const int qt = blockIdx.x, bh = blockIdx.y;
    const int b = bh / 12, h = bh % 12;
    const int t0 = qt*64;
    const int wq = tid>>6, lane = tid&63, g = lane>>4, cc = lane&15;
    const int srow = tid>>2, sgq = tid&3;    // staging: row 0..63, granule 0..3

    // ---- stage Q tile (already scaled bf16)
    {
        const unsigned short* qrow = qs + ((size_t)bh*1024 + t0 + srow)*64;
#pragma unroll
        for (int e=0;e<2;e++){
            const int gr = sgq + 4*e;
            *(s16x8*)&Qlds[srow*64 + ((gr ^ (srow&7))<<3)] = *(const s16x8*)(qrow + gr*8);
        }
    }
    __syncthreads();
    // ---- qred (q was scaled by 0.125 -> multiply back by 8)
    {
        const int t2 = tid>>2, r = tid&3;
        float s = 0.f;
#pragma unroll
        for (int gr=0; gr<8; gr++){
            s16x8 v8 = *(const s16x8*)&Qlds[t2*64 + ((gr ^ (t2&7))<<3)];
#pragma unroll
            for (int e=0;e<8;e++)
                s += bf2f((unsigned short)v8[e]) * red_w[r*64 + gr*8 + e];
        }
        qred_s[t2][r] = s * 8.f + red_b[r];
    }
    __syncthreads();

    // Q fragments
    s16x8 qf[2];
#pragma unroll
    for (int ks=0;ks<2;ks++){
        const int row = wq*16 + cc;
        qf[ks] = *(const s16x8*)&Qlds[row*64 + (((ks*4+g) ^ (row&7))<<3)];
    }
    // qred for this lane's dyn rows (local row = g + 4j)
    float4 qrd[4];
#pragma unroll
    for (int j=0;j<4;j++) qrd[j] = *(const float4*)&qred_s[wq*16 + g + 4*j][0];

    f32x4 accO[4];
#pragma unroll
    for (int i=0;i<4;i++) accO[i] = (f32x4){0.f,0.f,0.f,0.f};
    float mrow_[4], lrow_[4];
#pragma unroll
    for (int r=0;r<4;r++){ mrow_[r] = -1e30f; lrow_[r] = 0.f; }

    const unsigned short* kbase = kbf + ((size_t)bh*1024)*64;
    const unsigned short* vbase = vtf + ((size_t)bh*64 + srow)*1024;
    size_t kd_b[4], bias_b[4];
#pragma unroll
    for (int j=0;j<4;j++){
        const int tg = t0 + wq*16 + g + 4*j;
        kd_b[j]   = ((size_t)(bh*1024 + tg))*4096 + cc*4;
        bias_b[j] = ((size_t)bh*1024 + tg)*1024 + cc*4;
    }
    const int* mbase = kpm + b*1024 + cc*4;

    s16x8 kreg0, kreg1, vreg0, vreg1;
    float4 kA[8], kB[8], bs4[4], dynacc[4];
    int4 mm4;

    // ---- prologue: chunk 0 loads
    {
        const unsigned short* kp = kbase + (size_t)srow*64;
        kreg0 = *(const s16x8*)(kp + sgq*8);
        kreg1 = *(const s16x8*)(kp + (sgq+4)*8);
        vreg0 = *(const s16x8*)(vbase + sgq*8);
        vreg1 = *(const s16x8*)(vbase + (sgq+4)*8);
#pragma unroll
        for (int j=0;j<4;j++){
            kA[2*j]   = *(const float4*)(kdyn + kd_b[j]);
            kA[2*j+1] = *(const float4*)(kdyn + kd_b[j] + 1024);
            bs4[j]    = *(const float4*)(bias + bias_b[j]);
        }
        mm4 = *(const int4*)(mbase);
#pragma unroll
        for (int j=0;j<4;j++){
            kB[2*j]   = *(const float4*)(kdyn + kd_b[j] + 2048);
            kB[2*j+1] = *(const float4*)(kdyn + kd_b[j] + 3072);
        }
#pragma unroll
        for (int j=0;j<4;j++)
            dynacc[j] = fma4(qrd[j].y, kA[2*j+1], fma4(qrd[j].x, kA[2*j], make_float4(0,0,0,0)));
    }

    const float NINF = -__builtin_inff();
    for (int c = 0; c < 16; ++c) {
        __syncthreads();   // prev chunk's LDS reads done
        // ---- KV regs -> LDS (swizzled)
        {
            const int sw0 = ((sgq   ^ (srow&7))<<3);
            const int sw1 = (((sgq+4) ^ (srow&7))<<3);
            *(s16x8*)&Klds[srow*64 + sw0] = kreg0;
            *(s16x8*)&Klds[srow*64 + sw1] = kreg1;
            *(s16x8*)&Vtl[srow*64 + sw0] = vreg0;
            *(s16x8*)&Vtl[srow*64 + sw1] = vreg1;
        }
        // ---- finish dyn(c): + r2,r3 + bias, mask -> dynl (per-wave)
#pragma unroll
        for (int j=0;j<4;j++){
            float4 dv = dynacc[j];
            dv = fma4(qrd[j].z, kB[2*j],   dv);
            dv = fma4(qrd[j].w, kB[2*j+1], dv);
            dv.x += bs4[j].x; dv.y += bs4[j].y; dv.z += bs4[j].z; dv.w += bs4[j].w;
            dv.x = mm4.x ? NINF : dv.x;
            dv.y = mm4.y ? NINF : dv.y;
            dv.z = mm4.z ? NINF : dv.z;
            dv.w = mm4.w ? NINF : dv.w;
            *(float4*)&dynl[wq][(g + 4*j)*66 + cc*4] = dv;
        }
        __syncthreads();   // K/V visible to all waves

        const int s1 = c*64 + 64;
        const bool pf = (c < 15);
        if (pf){
            const unsigned short* kp = kbase + (size_t)(s1 + srow)*64;
            kreg0 = *(const s16x8*)(kp + sgq*8);
            kreg1 = *(const s16x8*)(kp + (sgq+4)*8);
            vreg0 = *(const s16x8*)(vbase + s1 + sgq*8);
            vreg1 = *(const s16x8*)(vbase + s1 + (sgq+4)*8);
#pragma unroll
            for (int j=0;j<4;j++){
                kA[2*j]   = *(const float4*)(kdyn + kd_b[j] + s1);
                kA[2*j+1] = *(const float4*)(kdyn + kd_b[j] + 1024 + s1);
                bs4[j]    = *(const float4*)(bias + bias_b[j] + s1);
            }
            mm4 = *(const int4*)(mbase + s1);
        }

        // ---- QK^T
        f32x4 sc[4];
        __builtin_amdgcn_s_setprio(1);
#pragma unroll
        for (int sq=0;sq<4;sq++){
            f32x4 z = (f32x4){0.f,0.f,0.f,0.f};
#pragma unroll
            for (int ks=0;ks<2;ks++){
                const int rowk = sq*16 + cc;
                s16x8 kf = *(const s16x8*)&Klds[rowk*64 + (((ks*4+g) ^ (rowk&7))<<3)];
                z = MFMA(qf[ks], kf, z);
            }
            sc[sq] = z;
        }
        __builtin_amdgcn_s_setprio(0);

        if (pf){
#pragma unroll
            for (int j=0;j<4;j++){
                kB[2*j]   = *(const float4*)(kdyn + kd_b[j] + 2048 + s1);
                kB[2*j+1] = *(const float4*)(kdyn + kd_b[j] + 3072 + s1);
            }
        }

        // ---- softmax
        float sscale[4];
#pragma unroll
        for (int r=0;r<4;r++){
            const int trow = g*4 + r;
            float v[4];
#pragma unroll
            for (int sq=0;sq<4;sq++)
                v[sq] = sc[sq][r] + dynl[wq][trow*66 + sq*16 + cc];
            float mx = fmaxf(fmaxf(v[0],v[1]), fmaxf(v[2],v[3]));
#pragma unroll
            for (int off=1; off<16; off<<=1) mx = fmaxf(mx, __shfl_xor(mx, off));
            const float mn = fmaxf(mrow_[r], mx);
            float ps = 0.f;
#pragma unroll
            for (int sq=0;sq<4;sq++){ v[sq] = __expf(v[sq]-mn); ps += v[sq]; }
#pragma unroll
            for (int off=1; off<16; off<<=1) ps += __shfl_xor(ps, off);
            const float scl = __expf(mrow_[r]-mn);
            mrow_[r] = mn; lrow_[r] = lrow_[r]*scl + ps;
            sscale[r] = scl;
#pragma unroll
            for (int sq=0;sq<4;sq++){
                const int col = sq*16 + cc;
                Plds[wq][trow*64 + (((col>>3) ^ (trow&7))<<3) + (col&7)] = f2bf(v[sq]);
            }
        }
#pragma unroll
        for (int dq=0;dq<4;dq++){
            f32x4 a = accO[dq];
            a[0]*=sscale[0]; a[1]*=sscale[1]; a[2]*=sscale[2]; a[3]*=sscale[3];
            accO[dq] = a;
        }

        if (pf){
#pragma unroll
            for (int j=0;j<4;j++)
                dynacc[j] = fma4(qrd[j].y, kA[2*j+1], fma4(qrd[j].x, kA[2*j], make_float4(0,0,0,0)));
        }

        // ---- PV
        __builtin_amdgcn_s_setprio(1);
#pragma unroll
        for (int ks=0;ks<2;ks++){
            s16x8 pfr = *(const s16x8*)&Plds[wq][cc*64 + (((ks*4+g) ^ (cc&7))<<3)];
#pragma unroll
            for (int dq=0;dq<4;dq++){
                const int rowv = dq*16 + cc;
                s16x8 vf = *(const s16x8*)&Vtl[rowv*64 + (((ks*4+g) ^ (rowv&7))<<3)];
                accO[dq] = MFMA(pfr, vf, accO[dq]);
            }
        }
        __builtin_amdgcn_s_setprio(0);
    }

    // ---- epilogue
#pragma unroll
    for (int dq=0;dq<4;dq++){
#pragma unroll
        for (int r=0;r<4;r++){
            const int t = t0 + wq*16 + g*4 + r;
            o[(size_t)(b*1024 + t)*768 + h*64 + dq*16 + cc] = accO[dq][r] / lrow_[r];
        }
    }
}

extern "C" void kernel_launch(void* const* d_in, const int* in_sizes, int n_in,
                              void* d_out, int out_size, void* d_ws, size_t ws_size,
                              hipStream_t stream) {
    const float* query = (const float*)d_in[0];
    const float* kdyn  = (const float*)d_in[1];
    const int*   kpm   = (const int*)d_in[2];
    const float* bias  = (const float*)d_in[3];
    const float* in_w  = (const float*)d_in[4];
    const float* in_b  = (const float*)d_in[5];
    const float* red_w = (const float*)d_in[6];
    const float* red_b = (const float*)d_in[7];
    const float* out_w = (const float*)d_in[8];
    const float* out_b = (const float*)d_in[9];
    float* out = (float*)d_out;

    const size_t SEG = (size_t)48*1024*64;           // 3,145,728 elems
    unsigned short* qs = (unsigned short*)d_ws;
    unsigned short* kb = qs + SEG;
    unsigned short* vt = kb + SEG;
    float* o = (float*)(vt + SEG);                   // [4096][768] f32

    gemm_qkv<<<dim3(18,32), 256, 0, stream>>>(query, in_w, in_b, qs, kb, vt);
    attn_mfma<<<dim3(16,48), 256, 0, stream>>>(qs, kb, vt, kdyn, kpm, bias, red_w, red_b, o);
    gemm_mfma<<<dim3(6,32),  256, 0, stream>>>(o, out_w, out_b, out, 768, 768);
}